// Round 3
// baseline (282.765 us; speedup 1.0000x reference)
//
#include <hip/hip_runtime.h>
#include <math.h>

#define BB 32
#define LL 200
#define HH 64
#define HSS 32
#define HB 64
#define NEGV (-4294967295.0f)

typedef __bf16 bf16x8 __attribute__((ext_vector_type(8)));
typedef float f32x4 __attribute__((ext_vector_type(4)));

// ---------------------------------------------------------------------------
// Kernel A: QKV projections into split-head layout  Qs/Ks/Vs [HB][L][HS]
// ---------------------------------------------------------------------------
__global__ __launch_bounds__(64) void proj_kernel(
    const float* __restrict__ q_in, const float* __restrict__ k_in,
    const float* __restrict__ v_in,
    const float* __restrict__ Wq, const float* __restrict__ bq,
    const float* __restrict__ Wk, const float* __restrict__ bk,
    const float* __restrict__ Wv, const float* __restrict__ bv,
    float* __restrict__ Qs, float* __restrict__ Ks, float* __restrict__ Vs)
{
    const int row = blockIdx.x;            // b*L + l
    const int b = row / LL, l = row % LL;
    const int j = threadIdx.x;             // output channel 0..63

    __shared__ float s[3][HH];
    s[0][j] = q_in[row*HH + j];
    s[1][j] = k_in[row*HH + j];
    s[2][j] = v_in[row*HH + j];
    __syncthreads();

    const float* W[3]    = {Wq, Wk, Wv};
    const float* bias[3] = {bq, bk, bv};
    float*       dst[3]  = {Qs, Ks, Vs};

    const int hb  = (j >> 5)*BB + b;                 // head*B + b
    const int idx = (hb*LL + l)*HSS + (j & 31);

    #pragma unroll
    for (int m = 0; m < 3; ++m) {
        float acc = bias[m][j];
        #pragma unroll
        for (int i = 0; i < HH; ++i)
            acc = fmaf(s[m][i], W[m][i*HH + j], acc);
        dst[m][idx] = acc;
    }
}

// ---------------------------------------------------------------------------
// Kernel P: Wt (fp32 [k][n]) -> WtT_bf16 [n][k]  (B-operand, N-major)
// ---------------------------------------------------------------------------
__global__ __launch_bounds__(256) void prep_kernel(
    const float* __restrict__ Wt, unsigned short* __restrict__ WtT)
{
    const int t = blockIdx.x*256 + threadIdx.x;      // t = n*64 + k
    if (t < HH*HH) {
        const int n = t >> 6, k = t & 63;
        const __bf16 h = (__bf16)Wt[k*HH + n];
        WtT[t] = __builtin_bit_cast(unsigned short, h);
    }
}

// ---------------------------------------------------------------------------
// Kernel B: MFMA time-bias MLP (T direct global->reg->bf16, NO LDS staging)
//           + QK^T + mask + softmax + PV
// one 256-thread block per (hb, q); wave w owns key tiles {c*64 + w*16}
// ---------------------------------------------------------------------------
__global__ __launch_bounds__(256) void attn_kernel(
    const float* __restrict__ Qs, const float* __restrict__ Ks,
    const float* __restrict__ Vs,
    const float* __restrict__ T,                 // [HB, L, L, H] fp32
    const int*   __restrict__ time_mask,         // [B, L] int32
    const unsigned short* __restrict__ WtT,      // bf16 [n][k]
    const float* __restrict__ bt, const float* __restrict__ Wp,
    const float* __restrict__ bp,
    float* __restrict__ out, float* __restrict__ attn_out)
{
    const int q    = blockIdx.x;
    const int hb   = blockIdx.y;
    const int b    = hb & (BB-1);
    const int head = hb >> 5;
    const int tid  = threadIdx.x;
    const int wave = tid >> 6;
    const int lane = tid & 63;
    const int bl   = lane & 15;                  // A-row-in-tile / B-col-in-tile
    const int bg   = lane >> 4;                  // k-group (8 elems each)

    __shared__ float sQ[HSS];
    __shared__ float sQK[LL];
    __shared__ float sLogit[LL];
    __shared__ float sRed[8];
    __shared__ float sO[8][HSS];

    // ---- B fragments (Wt), bt/Wp per-lane channel coefs ----
    bf16x8 bfrag[4][2];
    float  btv[4], wpv[4];
    #pragma unroll
    for (int n = 0; n < 4; ++n) {
        #pragma unroll
        for (int k = 0; k < 2; ++k) {
            const uint4 raw = *reinterpret_cast<const uint4*>(
                WtT + ((n*16 + bl)*HH + k*32 + bg*8));
            bfrag[n][k] = __builtin_bit_cast(bf16x8, raw);
        }
        btv[n] = bt[n*16 + bl];
        wpv[n] = Wp[n*16 + bl];
    }
    const float bp0 = bp[0];

    if (tid < HSS) sQ[tid] = Qs[(hb*LL + q)*HSS + tid];
    const bool qmask = (time_mask[b*LL + q] != 0);
    const float scale = 0.17677669529663687f;    // 1/sqrt(32)
    __syncthreads();

    // ---- QK^T row (fp32, once per block) ----
    if (tid < LL) {
        const float4* kr = reinterpret_cast<const float4*>(Ks + (hb*LL + tid)*HSS);
        float acc = 0.0f;
        #pragma unroll
        for (int i = 0; i < 8; ++i) {
            const float4 kv = kr[i];
            acc += kv.x*sQ[4*i+0] + kv.y*sQ[4*i+1]
                 + kv.z*sQ[4*i+2] + kv.w*sQ[4*i+3];
        }
        sQK[tid] = acc;
    }
    __syncthreads();   // sQK visible to all waves; no more barriers until softmax

    const float* Trow = T + (size_t)(hb*LL + q) * (LL*HH);

    // ---- 4 key-tiles per wave, barrier-free streaming ----
    #pragma unroll
    for (int c = 0; c < 4; ++c) {
        const int tileKey = c*64 + wave*16;
        if (tileKey < LL) {
            // A fragments straight from global (row clamped on tail; masked later)
            const int ar = min(tileKey + bl, LL-1);
            const float* src = Trow + ar*HH + bg*8;
            const float4 a0 = *reinterpret_cast<const float4*>(src);
            const float4 a1 = *reinterpret_cast<const float4*>(src + 4);
            const float4 a2 = *reinterpret_cast<const float4*>(src + 32);
            const float4 a3 = *reinterpret_cast<const float4*>(src + 36);

            bf16x8 afrag[2];
            afrag[0] = (bf16x8){(__bf16)a0.x, (__bf16)a0.y, (__bf16)a0.z, (__bf16)a0.w,
                                (__bf16)a1.x, (__bf16)a1.y, (__bf16)a1.z, (__bf16)a1.w};
            afrag[1] = (bf16x8){(__bf16)a2.x, (__bf16)a2.y, (__bf16)a2.z, (__bf16)a2.w,
                                (__bf16)a3.x, (__bf16)a3.y, (__bf16)a3.z, (__bf16)a3.w};

            f32x4 acc[4];
            #pragma unroll
            for (int n = 0; n < 4; ++n) {
                acc[n] = (f32x4){0.f, 0.f, 0.f, 0.f};
                acc[n] = __builtin_amdgcn_mfma_f32_16x16x32_bf16(
                             afrag[0], bfrag[n][0], acc[n], 0, 0, 0);
                acc[n] = __builtin_amdgcn_mfma_f32_16x16x32_bf16(
                             afrag[1], bfrag[n][1], acc[n], 0, 0, 0);
            }

            // epilogue: p[r] = sum_ch relu(S+bt)*Wp ; reduce over 16 col-lanes
            float p[4] = {0.f, 0.f, 0.f, 0.f};
            #pragma unroll
            for (int n = 0; n < 4; ++n) {
                #pragma unroll
                for (int r = 0; r < 4; ++r)
                    p[r] = fmaf(fmaxf(acc[n][r] + btv[n], 0.f), wpv[n], p[r]);
            }
            #pragma unroll
            for (int m = 1; m < 16; m <<= 1) {
                #pragma unroll
                for (int r = 0; r < 4; ++r) p[r] += __shfl_xor(p[r], m, 64);
            }
            if (bl == 0) {
                #pragma unroll
                for (int r = 0; r < 4; ++r) {
                    const int key = tileKey + bg*4 + r;
                    if (key < LL) {
                        const float x  = p[r] + bp0;
                        const float ls = -logf(1.0f + expf(-x)); // log(sigmoid)
                        float logit = (sQK[key] + ls) * scale;
                        if (qmask || key > q) logit = NEGV;
                        sLogit[key] = logit;
                    }
                }
            }
        }
    }
    __syncthreads();

    // ---- softmax over 200 logits ----
    const float v = (tid < LL) ? sLogit[tid] : -INFINITY;
    float mx = v;
    #pragma unroll
    for (int s = 1; s < 64; s <<= 1) mx = fmaxf(mx, __shfl_xor(mx, s, 64));
    if (lane == 0) sRed[wave] = mx;
    __syncthreads();
    const float rowmax = fmaxf(fmaxf(sRed[0], sRed[1]), fmaxf(sRed[2], sRed[3]));

    const float e = (tid < LL) ? expf(v - rowmax) : 0.0f;
    float sm = e;
    #pragma unroll
    for (int s = 1; s < 64; s <<= 1) sm += __shfl_xor(sm, s, 64);
    if (lane == 0) sRed[4 + wave] = sm;
    __syncthreads();
    const float rowsum = sRed[4] + sRed[5] + sRed[6] + sRed[7];
    const float a = e * (1.0f / rowsum);

    __syncthreads();           // sLogit reads above complete
    if (tid < LL) {
        sLogit[tid] = a;
        attn_out[((size_t)(hb*LL + q))*LL + tid] = a;
    }
    __syncthreads();

    // ---- out[d] = sum_k a[k] * V[hb][k][d] ----
    {
        const int d = tid & 31;
        const int g = tid >> 5;            // 0..7, 25 keys each
        float acc = 0.0f;
        for (int k = g*25; k < g*25 + 25; ++k)
            acc = fmaf(sLogit[k], Vs[(hb*LL + k)*HSS + d], acc);
        sO[g][d] = acc;
        __syncthreads();
        if (tid < HSS) {
            float o = 0.0f;
            #pragma unroll
            for (int g2 = 0; g2 < 8; ++g2) o += sO[g2][tid];
            out[((size_t)b*LL + q)*HH + head*HSS + tid] = o;
        }
    }
}

// ---------------------------------------------------------------------------
extern "C" void kernel_launch(void* const* d_in, const int* in_sizes, int n_in,
                              void* d_out, int out_size, void* d_ws, size_t ws_size,
                              hipStream_t stream) {
    const float* queries = (const float*)d_in[0];
    const float* keys    = (const float*)d_in[1];
    const float* values  = (const float*)d_in[2];
    const float* T       = (const float*)d_in[3];
    const int*   tmask   = (const int*)d_in[4];
    // d_in[5] = attn_mask (causal triu, computed on the fly -> unused)
    const float* Wq = (const float*)d_in[6];
    const float* bq = (const float*)d_in[7];
    const float* Wk = (const float*)d_in[8];
    const float* bk = (const float*)d_in[9];
    const float* Wv = (const float*)d_in[10];
    const float* bv = (const float*)d_in[11];
    const float* Wt = (const float*)d_in[12];
    const float* bt = (const float*)d_in[13];
    const float* Wp = (const float*)d_in[14];
    const float* bp = (const float*)d_in[15];

    float* Qs = (float*)d_ws;
    float* Ks = Qs + HB*LL*HSS;
    float* Vs = Ks + HB*LL*HSS;
    unsigned short* WtT = (unsigned short*)(Vs + HB*LL*HSS);

    float* out      = (float*)d_out;
    float* attn_out = out + BB*LL*HH;

    prep_kernel<<<16, 256, 0, stream>>>(Wt, WtT);
    proj_kernel<<<BB*LL, 64, 0, stream>>>(queries, keys, values,
                                          Wq, bq, Wk, bk, Wv, bv,
                                          Qs, Ks, Vs);

    dim3 grid(LL, HB);
    attn_kernel<<<grid, 256, 0, stream>>>(Qs, Ks, Vs, T, tmask,
                                          WtT, bt, Wp, bp, out, attn_out);
}

// Round 4
// 203.761 us; speedup vs baseline: 1.3877x; 1.3877x over previous
//
#include <hip/hip_runtime.h>
#include <math.h>

#define BB 32
#define LL 200
#define HH 64
#define HSS 32
#define HB 64
#define NEGV (-4294967295.0f)

typedef __bf16 bf16x8 __attribute__((ext_vector_type(8)));
typedef float f32x4 __attribute__((ext_vector_type(4)));

// ---------------------------------------------------------------------------
// Kernel A: QKV projections into split-head layout  Qs/Ks/Vs [HB][L][HS]
// ---------------------------------------------------------------------------
__global__ __launch_bounds__(64) void proj_kernel(
    const float* __restrict__ q_in, const float* __restrict__ k_in,
    const float* __restrict__ v_in,
    const float* __restrict__ Wq, const float* __restrict__ bq,
    const float* __restrict__ Wk, const float* __restrict__ bk,
    const float* __restrict__ Wv, const float* __restrict__ bv,
    float* __restrict__ Qs, float* __restrict__ Ks, float* __restrict__ Vs)
{
    const int row = blockIdx.x;            // b*L + l
    const int b = row / LL, l = row % LL;
    const int j = threadIdx.x;             // output channel 0..63

    __shared__ float s[3][HH];
    s[0][j] = q_in[row*HH + j];
    s[1][j] = k_in[row*HH + j];
    s[2][j] = v_in[row*HH + j];
    __syncthreads();

    const float* W[3]    = {Wq, Wk, Wv};
    const float* bias[3] = {bq, bk, bv};
    float*       dst[3]  = {Qs, Ks, Vs};

    const int hb  = (j >> 5)*BB + b;                 // head*B + b
    const int idx = (hb*LL + l)*HSS + (j & 31);

    #pragma unroll
    for (int m = 0; m < 3; ++m) {
        float acc = bias[m][j];
        #pragma unroll
        for (int i = 0; i < HH; ++i)
            acc = fmaf(s[m][i], W[m][i*HH + j], acc);
        dst[m][idx] = acc;
    }
}

// ---------------------------------------------------------------------------
// Kernel P: Wt (fp32 [k][n]) -> WtT_bf16 [n][k]  (B-operand, N-major)
// ---------------------------------------------------------------------------
__global__ __launch_bounds__(256) void prep_kernel(
    const float* __restrict__ Wt, unsigned short* __restrict__ WtT)
{
    const int t = blockIdx.x*256 + threadIdx.x;      // t = n*64 + k
    if (t < HH*HH) {
        const int n = t >> 6, k = t & 63;
        const __bf16 h = (__bf16)Wt[k*HH + n];
        WtT[t] = __builtin_bit_cast(unsigned short, h);
    }
}

// ---------------------------------------------------------------------------
// Kernel B: MFMA time-bias MLP, double-buffered LDS + issue-early pipeline
//           + QK^T + mask + softmax + PV
// one 256-thread block per (hb, q); wave w owns key tile {c*64 + w*16}
// ---------------------------------------------------------------------------
__global__ __launch_bounds__(256) void attn_kernel(
    const float* __restrict__ Qs, const float* __restrict__ Ks,
    const float* __restrict__ Vs,
    const float* __restrict__ T,                 // [HB, L, L, H] fp32
    const int*   __restrict__ time_mask,         // [B, L] int32
    const unsigned short* __restrict__ WtT,      // bf16 [n][k]
    const float* __restrict__ bt, const float* __restrict__ Wp,
    const float* __restrict__ bp,
    float* __restrict__ out, float* __restrict__ attn_out)
{
    const int q    = blockIdx.x;
    const int hb   = blockIdx.y;
    const int b    = hb & (BB-1);
    const int head = hb >> 5;
    const int tid  = threadIdx.x;
    const int wave = tid >> 6;
    const int lane = tid & 63;
    const int bl   = lane & 15;                  // A-row-in-tile / B-col-in-tile
    const int bg   = lane >> 4;                  // k-group (8 elems each)

    __shared__ __align__(16) unsigned short sA[2][64*HH];  // 2 x 8 KB, swizzled
    __shared__ float sQ[HSS];
    __shared__ float sQK[LL];
    __shared__ float sLogit[LL];
    __shared__ float sRed[8];
    __shared__ float sO[8][HSS];

    const float* Trow = T + (size_t)(hb*LL + q) * (LL*HH);
    const float4* Trow4 = reinterpret_cast<const float4*>(Trow);

    // ---- issue chunk-0 loads FIRST (latency hides under setup below) ----
    float4 va[4];
    #pragma unroll
    for (int i = 0; i < 4; ++i) va[i] = Trow4[i*256 + tid];

    // ---- B fragments (Wt), bt/Wp per-lane channel coefs ----
    bf16x8 bfrag[4][2];
    float  btv[4], wpv[4];
    #pragma unroll
    for (int n = 0; n < 4; ++n) {
        #pragma unroll
        for (int k = 0; k < 2; ++k) {
            const uint4 raw = *reinterpret_cast<const uint4*>(
                WtT + ((n*16 + bl)*HH + k*32 + bg*8));
            bfrag[n][k] = __builtin_bit_cast(bf16x8, raw);
        }
        btv[n] = bt[n*16 + bl];
        wpv[n] = Wp[n*16 + bl];
    }
    const float bp0 = bp[0];

    if (tid < HSS) sQ[tid] = Qs[(hb*LL + q)*HSS + tid];
    const bool qmask = (time_mask[b*LL + q] != 0);
    const float scale = 0.17677669529663687f;    // 1/sqrt(32)
    __syncthreads();

    // ---- QK^T row (fp32, once per block) ----
    if (tid < LL) {
        const float4* kr = reinterpret_cast<const float4*>(Ks + (hb*LL + tid)*HSS);
        float acc = 0.0f;
        #pragma unroll
        for (int i = 0; i < 8; ++i) {
            const float4 kv = kr[i];
            acc += kv.x*sQ[4*i+0] + kv.y*sQ[4*i+1]
                 + kv.z*sQ[4*i+2] + kv.w*sQ[4*i+3];
        }
        sQK[tid] = acc;
    }
    __syncthreads();   // sQK visible to all waves

    // ---- pipelined chunks: stage c (regs->LDS), issue c+1, compute c ----
    #pragma unroll
    for (int c = 0; c < 4; ++c) {
        // pack chunk c (waits vmcnt on va) and store to LDS buffer c&1
        #pragma unroll
        for (int i = 0; i < 4; ++i) {
            const int g = i*256 + tid;           // chunk-local float4 idx
            const int row = g >> 4, cf4 = g & 15;
            union { __bf16 h[4]; uint2 u2; } pk;
            pk.h[0] = (__bf16)va[i].x; pk.h[1] = (__bf16)va[i].y;
            pk.h[2] = (__bf16)va[i].z; pk.h[3] = (__bf16)va[i].w;
            const int byteoff = row*128 + ((cf4*8) ^ ((row & 7) << 4));
            *reinterpret_cast<uint2*>(
                reinterpret_cast<char*>(sA[c & 1]) + byteoff) = pk.u2;
        }
        // issue chunk c+1 loads (WAR on va sequences after the cvts above;
        // stays in flight across the barrier and the compute phase)
        if (c < 3) {
            #pragma unroll
            for (int i = 0; i < 4; ++i) {
                const int g = i*256 + tid;
                if (c + 1 < 3 || g < 8*16)
                    va[i] = Trow4[(c+1)*1024 + g];
                else
                    va[i] = make_float4(0.f, 0.f, 0.f, 0.f);
            }
        }
        __syncthreads();

        const int tileKey = c*64 + wave*16;      // this wave's M-tile base
        if (tileKey < LL) {
            // A fragments from swizzled LDS
            const int arow = wave*16 + bl;       // chunk-local row
            bf16x8 afrag[2];
            #pragma unroll
            for (int k = 0; k < 2; ++k) {
                const int abyte = arow*128 + ((k*64 + bg*16) ^ ((arow & 7) << 4));
                const uint4 raw = *reinterpret_cast<const uint4*>(
                    reinterpret_cast<const char*>(sA[c & 1]) + abyte);
                afrag[k] = __builtin_bit_cast(bf16x8, raw);
            }

            f32x4 acc[4];
            #pragma unroll
            for (int n = 0; n < 4; ++n) {
                acc[n] = (f32x4){0.f, 0.f, 0.f, 0.f};
                acc[n] = __builtin_amdgcn_mfma_f32_16x16x32_bf16(
                             afrag[0], bfrag[n][0], acc[n], 0, 0, 0);
                acc[n] = __builtin_amdgcn_mfma_f32_16x16x32_bf16(
                             afrag[1], bfrag[n][1], acc[n], 0, 0, 0);
            }

            // epilogue: p[r] = sum_ch relu(S+bt)*Wp ; reduce over 16 col-lanes
            float p[4] = {0.f, 0.f, 0.f, 0.f};
            #pragma unroll
            for (int n = 0; n < 4; ++n) {
                #pragma unroll
                for (int r = 0; r < 4; ++r)
                    p[r] = fmaf(fmaxf(acc[n][r] + btv[n], 0.f), wpv[n], p[r]);
            }
            #pragma unroll
            for (int m = 1; m < 16; m <<= 1) {
                #pragma unroll
                for (int r = 0; r < 4; ++r) p[r] += __shfl_xor(p[r], m, 64);
            }
            if (bl == 0) {
                #pragma unroll
                for (int r = 0; r < 4; ++r) {
                    const int key = tileKey + bg*4 + r;
                    if (key < LL) {
                        const float x  = p[r] + bp0;
                        const float ls = -logf(1.0f + expf(-x)); // log(sigmoid)
                        float logit = (sQK[key] + ls) * scale;
                        if (qmask || key > q) logit = NEGV;
                        sLogit[key] = logit;
                    }
                }
            }
        }
        __syncthreads();
    }

    // ---- softmax over 200 logits ----
    const float v = (tid < LL) ? sLogit[tid] : -INFINITY;
    float mx = v;
    #pragma unroll
    for (int s = 1; s < 64; s <<= 1) mx = fmaxf(mx, __shfl_xor(mx, s, 64));
    if (lane == 0) sRed[wave] = mx;
    __syncthreads();
    const float rowmax = fmaxf(fmaxf(sRed[0], sRed[1]), fmaxf(sRed[2], sRed[3]));

    const float e = (tid < LL) ? expf(v - rowmax) : 0.0f;
    float sm = e;
    #pragma unroll
    for (int s = 1; s < 64; s <<= 1) sm += __shfl_xor(sm, s, 64);
    if (lane == 0) sRed[4 + wave] = sm;
    __syncthreads();
    const float rowsum = sRed[4] + sRed[5] + sRed[6] + sRed[7];
    const float a = e * (1.0f / rowsum);

    __syncthreads();           // sLogit reads above complete
    if (tid < LL) {
        sLogit[tid] = a;
        attn_out[((size_t)(hb*LL + q))*LL + tid] = a;
    }
    __syncthreads();

    // ---- out[d] = sum_k a[k] * V[hb][k][d] ----
    {
        const int d = tid & 31;
        const int g = tid >> 5;            // 0..7, 25 keys each
        float acc = 0.0f;
        for (int k = g*25; k < g*25 + 25; ++k)
            acc = fmaf(sLogit[k], Vs[(hb*LL + k)*HSS + d], acc);
        sO[g][d] = acc;
        __syncthreads();
        if (tid < HSS) {
            float o = 0.0f;
            #pragma unroll
            for (int g2 = 0; g2 < 8; ++g2) o += sO[g2][tid];
            out[((size_t)b*LL + q)*HH + head*HSS + tid] = o;
        }
    }
}

// ---------------------------------------------------------------------------
extern "C" void kernel_launch(void* const* d_in, const int* in_sizes, int n_in,
                              void* d_out, int out_size, void* d_ws, size_t ws_size,
                              hipStream_t stream) {
    const float* queries = (const float*)d_in[0];
    const float* keys    = (const float*)d_in[1];
    const float* values  = (const float*)d_in[2];
    const float* T       = (const float*)d_in[3];
    const int*   tmask   = (const int*)d_in[4];
    // d_in[5] = attn_mask (causal triu, computed on the fly -> unused)
    const float* Wq = (const float*)d_in[6];
    const float* bq = (const float*)d_in[7];
    const float* Wk = (const float*)d_in[8];
    const float* bk = (const float*)d_in[9];
    const float* Wv = (const float*)d_in[10];
    const float* bv = (const float*)d_in[11];
    const float* Wt = (const float*)d_in[12];
    const float* bt = (const float*)d_in[13];
    const float* Wp = (const float*)d_in[14];
    const float* bp = (const float*)d_in[15];

    float* Qs = (float*)d_ws;
    float* Ks = Qs + HB*LL*HSS;
    float* Vs = Ks + HB*LL*HSS;
    unsigned short* WtT = (unsigned short*)(Vs + HB*LL*HSS);

    float* out      = (float*)d_out;
    float* attn_out = out + BB*LL*HH;

    prep_kernel<<<16, 256, 0, stream>>>(Wt, WtT);
    proj_kernel<<<BB*LL, 64, 0, stream>>>(queries, keys, values,
                                          Wq, bq, Wk, bk, Wv, bv,
                                          Qs, Ks, Vs);

    dim3 grid(LL, HB);
    attn_kernel<<<grid, 256, 0, stream>>>(Qs, Ks, Vs, T, tmask,
                                          WtT, bt, Wp, bp, out, attn_out);
}

// Round 5
// 200.284 us; speedup vs baseline: 1.4118x; 1.0174x over previous
//
#include <hip/hip_runtime.h>
#include <math.h>

#define BB 32
#define LL 200
#define HH 64
#define HSS 32
#define HB 64
#define NEGV (-4294967295.0f)

typedef __bf16 bf16x8 __attribute__((ext_vector_type(8)));
typedef float f32x4 __attribute__((ext_vector_type(4)));

// ---------------------------------------------------------------------------
// Kernel A: QKV projections into split-head layout  Qs/Ks/Vs [HB][L][HS]
// ---------------------------------------------------------------------------
__global__ __launch_bounds__(64) void proj_kernel(
    const float* __restrict__ q_in, const float* __restrict__ k_in,
    const float* __restrict__ v_in,
    const float* __restrict__ Wq, const float* __restrict__ bq,
    const float* __restrict__ Wk, const float* __restrict__ bk,
    const float* __restrict__ Wv, const float* __restrict__ bv,
    float* __restrict__ Qs, float* __restrict__ Ks, float* __restrict__ Vs)
{
    const int row = blockIdx.x;            // b*L + l
    const int b = row / LL, l = row % LL;
    const int j = threadIdx.x;             // output channel 0..63

    __shared__ float s[3][HH];
    s[0][j] = q_in[row*HH + j];
    s[1][j] = k_in[row*HH + j];
    s[2][j] = v_in[row*HH + j];
    __syncthreads();

    const float* W[3]    = {Wq, Wk, Wv};
    const float* bias[3] = {bq, bk, bv};
    float*       dst[3]  = {Qs, Ks, Vs};

    const int hb  = (j >> 5)*BB + b;                 // head*B + b
    const int idx = (hb*LL + l)*HSS + (j & 31);

    #pragma unroll
    for (int m = 0; m < 3; ++m) {
        float acc = bias[m][j];
        #pragma unroll
        for (int i = 0; i < HH; ++i)
            acc = fmaf(s[m][i], W[m][i*HH + j], acc);
        dst[m][idx] = acc;
    }
}

// ---------------------------------------------------------------------------
// Kernel P: Wt (fp32 [k][n]) -> WtT_bf16 [n][k]  (B-operand, N-major)
// ---------------------------------------------------------------------------
__global__ __launch_bounds__(256) void prep_kernel(
    const float* __restrict__ Wt, unsigned short* __restrict__ WtT)
{
    const int t = blockIdx.x*256 + threadIdx.x;      // t = n*64 + k
    if (t < HH*HH) {
        const int n = t >> 6, k = t & 63;
        const __bf16 h = (__bf16)Wt[k*HH + n];
        WtT[t] = __builtin_bit_cast(unsigned short, h);
    }
}

// ---------------------------------------------------------------------------
// Kernel B: MFMA time-bias MLP, 2-deep register pipeline + raw lgkm-only
//           barriers (NO vmcnt drain) + QK^T + mask + softmax + PV
// ---------------------------------------------------------------------------
__global__ __launch_bounds__(256) void attn_kernel(
    const float* __restrict__ Qs, const float* __restrict__ Ks,
    const float* __restrict__ Vs,
    const float* __restrict__ T,                 // [HB, L, L, H] fp32
    const int*   __restrict__ time_mask,         // [B, L] int32
    const unsigned short* __restrict__ WtT,      // bf16 [n][k]
    const float* __restrict__ bt, const float* __restrict__ Wp,
    const float* __restrict__ bp,
    float* __restrict__ out, float* __restrict__ attn_out)
{
    const int q    = blockIdx.x;
    const int hb   = blockIdx.y;
    const int b    = hb & (BB-1);
    const int head = hb >> 5;
    const int tid  = threadIdx.x;
    const int wave = tid >> 6;
    const int lane = tid & 63;
    const int bl   = lane & 15;                  // A-row-in-tile / B-col-in-tile
    const int bg   = lane >> 4;                  // k-group (8 elems each)

    __shared__ __align__(16) unsigned short sA[2][64*HH];  // 2 x 8 KB, swizzled
    __shared__ float sQ[HSS];
    __shared__ float sQK[LL];
    __shared__ float sLogit[LL];
    __shared__ float sRed[8];
    __shared__ float sO[8][HSS];

    const float* Trow = T + (size_t)(hb*LL + q) * (LL*HH);
    const float4* Trow4 = reinterpret_cast<const float4*>(Trow);

    // ---- issue chunk 0 AND chunk 1 loads first (2-deep pipeline) ----
    float4 va[4], vb[4];
    #pragma unroll
    for (int i = 0; i < 4; ++i) va[i] = Trow4[i*256 + tid];
    #pragma unroll
    for (int i = 0; i < 4; ++i) vb[i] = Trow4[1024 + i*256 + tid];

    // ---- B fragments (Wt), bt/Wp per-lane channel coefs ----
    bf16x8 bfrag[4][2];
    float  btv[4], wpv[4];
    #pragma unroll
    for (int n = 0; n < 4; ++n) {
        #pragma unroll
        for (int k = 0; k < 2; ++k) {
            const uint4 raw = *reinterpret_cast<const uint4*>(
                WtT + ((n*16 + bl)*HH + k*32 + bg*8));
            bfrag[n][k] = __builtin_bit_cast(bf16x8, raw);
        }
        btv[n] = bt[n*16 + bl];
        wpv[n] = Wp[n*16 + bl];
    }
    const float bp0 = bp[0];

    if (tid < HSS) sQ[tid] = Qs[(hb*LL + q)*HSS + tid];
    const bool qmask = (time_mask[b*LL + q] != 0);
    const float scale = 0.17677669529663687f;    // 1/sqrt(32)

    // sQ visible before QK reads; lgkm-only barrier (loads stay in flight)
    asm volatile("s_waitcnt lgkmcnt(0)" ::: "memory");
    __builtin_amdgcn_s_barrier();

    // ---- QK^T row (fp32, once per block) ----
    if (tid < LL) {
        const float4* kr = reinterpret_cast<const float4*>(Ks + (hb*LL + tid)*HSS);
        float acc = 0.0f;
        #pragma unroll
        for (int i = 0; i < 8; ++i) {
            const float4 kv = kr[i];
            acc += kv.x*sQ[4*i+0] + kv.y*sQ[4*i+1]
                 + kv.z*sQ[4*i+2] + kv.w*sQ[4*i+3];
        }
        sQK[tid] = acc;     // visible after the barrier inside CHUNK(0)
    }

    // ---- per-chunk macro: pack CUR -> sA[c&1]; reissue; barrier; compute ----
#define PACK_ISSUE_COMPUTE(c, CUR, DO_ISSUE, NC)                               \
    {                                                                          \
        /* pack chunk c (compiler waits vmcnt on CUR) into LDS buffer c&1 */   \
        _Pragma("unroll")                                                      \
        for (int i = 0; i < 4; ++i) {                                          \
            const int g = i*256 + tid;                                         \
            const int row = g >> 4, cf4 = g & 15;                              \
            union { __bf16 h[4]; uint2 u2; } pk;                               \
            pk.h[0] = (__bf16)CUR[i].x; pk.h[1] = (__bf16)CUR[i].y;            \
            pk.h[2] = (__bf16)CUR[i].z; pk.h[3] = (__bf16)CUR[i].w;            \
            const int byteoff = row*128 + ((cf4*8) ^ ((row & 7) << 4));        \
            *reinterpret_cast<uint2*>(                                         \
                reinterpret_cast<char*>(sA[(c) & 1]) + byteoff) = pk.u2;       \
        }                                                                      \
        if (DO_ISSUE) {   /* reissue CUR for chunk NC (WAR after pack) */      \
            _Pragma("unroll")                                                  \
            for (int i = 0; i < 4; ++i) {                                      \
                const int g = i*256 + tid;                                     \
                if ((NC) < 3 || g < 8*16)                                      \
                    CUR[i] = Trow4[(NC)*1024 + g];                             \
                else                                                           \
                    CUR[i] = make_float4(0.f, 0.f, 0.f, 0.f);                  \
            }                                                                  \
        }                                                                      \
        /* lgkm-only barrier: ds_writes visible, global loads NOT drained */   \
        asm volatile("s_waitcnt lgkmcnt(0)" ::: "memory");                     \
        __builtin_amdgcn_s_barrier();                                          \
                                                                               \
        const int tileKey = (c)*64 + wave*16;                                  \
        if (tileKey < LL) {                                                    \
            const int arow = wave*16 + bl;                                     \
            bf16x8 afrag[2];                                                   \
            _Pragma("unroll")                                                  \
            for (int k = 0; k < 2; ++k) {                                      \
                const int abyte = arow*128 + ((k*64 + bg*16) ^ ((arow & 7) << 4)); \
                const uint4 raw = *reinterpret_cast<const uint4*>(             \
                    reinterpret_cast<const char*>(sA[(c) & 1]) + abyte);       \
                afrag[k] = __builtin_bit_cast(bf16x8, raw);                    \
            }                                                                  \
            f32x4 acc[4];                                                      \
            _Pragma("unroll")                                                  \
            for (int n = 0; n < 4; ++n) {                                      \
                acc[n] = (f32x4){0.f, 0.f, 0.f, 0.f};                          \
                acc[n] = __builtin_amdgcn_mfma_f32_16x16x32_bf16(              \
                             afrag[0], bfrag[n][0], acc[n], 0, 0, 0);          \
                acc[n] = __builtin_amdgcn_mfma_f32_16x16x32_bf16(              \
                             afrag[1], bfrag[n][1], acc[n], 0, 0, 0);          \
            }                                                                  \
            float p[4] = {0.f, 0.f, 0.f, 0.f};                                 \
            _Pragma("unroll")                                                  \
            for (int n = 0; n < 4; ++n) {                                      \
                _Pragma("unroll")                                              \
                for (int r = 0; r < 4; ++r)                                    \
                    p[r] = fmaf(fmaxf(acc[n][r] + btv[n], 0.f), wpv[n], p[r]); \
            }                                                                  \
            _Pragma("unroll")                                                  \
            for (int m = 1; m < 16; m <<= 1) {                                 \
                _Pragma("unroll")                                              \
                for (int r = 0; r < 4; ++r) p[r] += __shfl_xor(p[r], m, 64);   \
            }                                                                  \
            if (bl == 0) {                                                     \
                _Pragma("unroll")                                              \
                for (int r = 0; r < 4; ++r) {                                  \
                    const int key = tileKey + bg*4 + r;                        \
                    if (key < LL) {                                            \
                        const float x  = p[r] + bp0;                           \
                        const float ls = -logf(1.0f + expf(-x));               \
                        float logit = (sQK[key] + ls) * scale;                 \
                        if (qmask || key > q) logit = NEGV;                    \
                        sLogit[key] = logit;                                   \
                    }                                                          \
                }                                                              \
            }                                                                  \
        }                                                                      \
    }

    PACK_ISSUE_COMPUTE(0, va, 1, 2)   // pack c0, reissue va <- chunk 2
    PACK_ISSUE_COMPUTE(1, vb, 1, 3)   // pack c1, reissue vb <- chunk 3 (tail)
    PACK_ISSUE_COMPUTE(2, va, 0, 0)
    PACK_ISSUE_COMPUTE(3, vb, 0, 0)
#undef PACK_ISSUE_COMPUTE

    __syncthreads();

    // ---- softmax over 200 logits ----
    const float v = (tid < LL) ? sLogit[tid] : -INFINITY;
    float mx = v;
    #pragma unroll
    for (int s = 1; s < 64; s <<= 1) mx = fmaxf(mx, __shfl_xor(mx, s, 64));
    if (lane == 0) sRed[wave] = mx;
    __syncthreads();
    const float rowmax = fmaxf(fmaxf(sRed[0], sRed[1]), fmaxf(sRed[2], sRed[3]));

    const float e = (tid < LL) ? expf(v - rowmax) : 0.0f;
    float sm = e;
    #pragma unroll
    for (int s = 1; s < 64; s <<= 1) sm += __shfl_xor(sm, s, 64);
    if (lane == 0) sRed[4 + wave] = sm;
    __syncthreads();
    const float rowsum = sRed[4] + sRed[5] + sRed[6] + sRed[7];
    const float a = e * (1.0f / rowsum);

    __syncthreads();           // sLogit reads above complete
    if (tid < LL) {
        sLogit[tid] = a;
        attn_out[((size_t)(hb*LL + q))*LL + tid] = a;
    }
    __syncthreads();

    // ---- out[d] = sum_k a[k] * V[hb][k][d] ----
    {
        const int d = tid & 31;
        const int g = tid >> 5;            // 0..7, 25 keys each
        float acc = 0.0f;
        for (int k = g*25; k < g*25 + 25; ++k)
            acc = fmaf(sLogit[k], Vs[(hb*LL + k)*HSS + d], acc);
        sO[g][d] = acc;
        __syncthreads();
        if (tid < HSS) {
            float o = 0.0f;
            #pragma unroll
            for (int g2 = 0; g2 < 8; ++g2) o += sO[g2][tid];
            out[((size_t)b*LL + q)*HH + head*HSS + tid] = o;
        }
    }
}

// ---------------------------------------------------------------------------
extern "C" void kernel_launch(void* const* d_in, const int* in_sizes, int n_in,
                              void* d_out, int out_size, void* d_ws, size_t ws_size,
                              hipStream_t stream) {
    const float* queries = (const float*)d_in[0];
    const float* keys    = (const float*)d_in[1];
    const float* values  = (const float*)d_in[2];
    const float* T       = (const float*)d_in[3];
    const int*   tmask   = (const int*)d_in[4];
    // d_in[5] = attn_mask (causal triu, computed on the fly -> unused)
    const float* Wq = (const float*)d_in[6];
    const float* bq = (const float*)d_in[7];
    const float* Wk = (const float*)d_in[8];
    const float* bk = (const float*)d_in[9];
    const float* Wv = (const float*)d_in[10];
    const float* bv = (const float*)d_in[11];
    const float* Wt = (const float*)d_in[12];
    const float* bt = (const float*)d_in[13];
    const float* Wp = (const float*)d_in[14];
    const float* bp = (const float*)d_in[15];

    float* Qs = (float*)d_ws;
    float* Ks = Qs + HB*LL*HSS;
    float* Vs = Ks + HB*LL*HSS;
    unsigned short* WtT = (unsigned short*)(Vs + HB*LL*HSS);

    float* out      = (float*)d_out;
    float* attn_out = out + BB*LL*HH;

    prep_kernel<<<16, 256, 0, stream>>>(Wt, WtT);
    proj_kernel<<<BB*LL, 64, 0, stream>>>(queries, keys, values,
                                          Wq, bq, Wk, bk, Wv, bv,
                                          Qs, Ks, Vs);

    dim3 grid(LL, HB);
    attn_kernel<<<grid, 256, 0, stream>>>(Qs, Ks, Vs, T, tmask,
                                          WtT, bt, Wp, bp, out, attn_out);
}